// Round 9
// baseline (937.586 us; speedup 1.0000x reference)
//
#include <hip/hip_runtime.h>
#include <hip/hip_bf16.h>

#define DIM   384
#define NWIN  49
#define HEADS 12
#define SCALE 0.17677669529663687f

typedef unsigned short ushort;
using bf16x8 = __attribute__((ext_vector_type(8))) short;
using u16x4  = __attribute__((ext_vector_type(4))) ushort;
using f32x4  = __attribute__((ext_vector_type(4))) float;

__device__ __forceinline__ ushort f2bf(float f) {
  unsigned u = __float_as_uint(f);
  u += 0x7fff + ((u >> 16) & 1);          // RNE
  return (ushort)(u >> 16);
}

typedef __attribute__((address_space(1))) const void gas_void;
typedef __attribute__((address_space(3))) void las_void;

__device__ __forceinline__ void gload16(const ushort* g, ushort* l) {
  __builtin_amdgcn_global_load_lds((gas_void*)g, (las_void*)l, 16, 0, 0);
}

// ===================== prep =====================
__global__ void prep_kernel(const float* __restrict__ qkv_w, const float* __restrict__ proj_w,
                            const float* __restrict__ bias_table, const int* __restrict__ rel_index,
                            const float* __restrict__ mask, const float* __restrict__ qkv_b,
                            ushort* __restrict__ wqb, ushort* __restrict__ wpb,
                            float* __restrict__ qbF, float* __restrict__ bmF) {
  int i0 = blockIdx.x * 256 + threadIdx.x;
  int stride = gridDim.x * 256;
  for (int i = i0; i < 1152 * 384; i += stride) {
    float v = qkv_w[i];
    if (i < 384 * 384) v *= SCALE;                 // fold softmax scale into Wq
    wqb[i] = f2bf(v);
  }
  for (int i = i0; i < 384 * 384; i += stride) wpb[i] = f2bf(proj_w[i]);
  for (int i = i0; i < 1152; i += stride) qbF[i] = qkv_b[i] * (i < 384 ? SCALE : 1.f);
  // bmF[wdx][h][wq][kt][lane][r], masking baked in
  for (int i = i0; i < 64 * HEADS * 4 * 4 * 64 * 4; i += stride) {
    int r = i & 3, lane = (i >> 2) & 63, kt = (i >> 8) & 3, wq = (i >> 10) & 3;
    int hw = i >> 12;
    int h = hw % HEADS, wdx = hw / HEADS;
    int q = wq * 16 + (lane >> 4) * 4 + r;
    int key = kt * 16 + (lane & 15);
    float v;
    if (q < NWIN)
      v = (key < NWIN) ? bias_table[rel_index[q * NWIN + key] * HEADS + h]
                         + mask[wdx * (NWIN * NWIN) + q * NWIN + key]
                       : -3.0e38f;
    else
      v = 0.f;
    bmF[i] = v;
  }
}

// ===================== kernel 2: QKV GEMM + attention (2 windows/block, 512 thr) ==========
// LDS map (ushort units):
//  WB [0,24576)      : 2 x [96][128] weight chunks; x staged here first (18816 us/window)
//  QS [24576,29440)  : 2 win x [64][38]  (q rows, later P rows)
//  KS [29440,34304)  : 2 win x [64][38]
//  VT [34304,39040)  : 2 win x [32][74]  (v^T [d][tok])
#define WB_OFF 0
#define QS_OFF 24576
#define KS_OFF 29440
#define VT_OFF 34304
#define SMEM2_US 39040   // 78080 bytes -> 2 blocks/CU

__global__ __launch_bounds__(512, 2) void qkv_attn_kernel(
    const float* __restrict__ x, const float* __restrict__ qbF,
    const ushort* __restrict__ wqb, const float* __restrict__ bmF,
    ushort* __restrict__ aog)
{
  extern __shared__ ushort smem[];
  ushort* wb = smem + WB_OFF;

  const int blk = blockIdx.x;
  const int tid = threadIdx.x;
  const int w = tid >> 6, l = tid & 63;
  const int c = l & 15, g = l >> 4;
  const int wm = w >> 1, wn = w & 1;    // GEMM: 4M x 2N, wave tile 32 x 48
  const int win = w >> 2, wq = w & 3;   // attention: 2 windows x 4 q-tiles
  const float LOG2E = 1.4426950408889634f;

  // stage one [96 n][128 k] qkv chunk into wb half `buf` (src-side xor swizzle)
  auto stage_qkv = [&](int h, int kc, int buf) {
    #pragma unroll
    for (int s = 0; s < 3; ++s) {
      int i = s * 512 + tid;            // 1536 granules exactly
      int n = i >> 4, g16 = i & 15;
      int grow = (n >> 5) * 384 + h * 32 + (n & 31);
      int sg = (g16 & 8) | ((g16 & 7) ^ (n & 7));
      gload16(wqb + (size_t)grow * DIM + kc * 128 + (sg << 3),
              wb + buf * 12288 + i * 8);
    }
  };

  bf16x8 areg[2][12] = {};
  auto compute_qkv = [&](int kcC, int buf, f32x4 (&acc)[2][3]) {
    const ushort* wcb = wb + buf * 12288;
    #pragma unroll
    for (int kk = 0; kk < 4; ++kk) {
      int sB = ((kk * 4 + g) ^ (c & 7)) << 3;
      #pragma unroll
      for (int nt = 0; nt < 3; ++nt) {
        int n = (wn * 3 + nt) * 16 + c;
        bf16x8 bb = *(const bf16x8*)&wcb[n * 128 + sB];
        acc[0][nt] = __builtin_amdgcn_mfma_f32_16x16x32_bf16(areg[0][kcC * 4 + kk], bb, acc[0][nt], 0, 0, 0);
        acc[1][nt] = __builtin_amdgcn_mfma_f32_16x16x32_bf16(areg[1][kcC * 4 + kk], bb, acc[1][nt], 0, 0, 0);
      }
    }
  };

  // ---- prologue: stage x per window through wb region, load A-regs
  #pragma unroll
  for (int wi = 0; wi < 2; ++wi) {
    const float* xb = x + (size_t)((blk << 1) + wi) * (NWIN * DIM);
    for (int i = tid; i < 4704; i += 512) {        // 4704 float4 = 49*384 floats
      float4 f = ((const float4*)xb)[i];
      int row = i / 96, c4 = i - row * 96;
      u16x4 v4 = { f2bf(f.x), f2bf(f.y), f2bf(f.z), f2bf(f.w) };
      *(u16x4*)&wb[row * 384 + c4 * 4] = v4;
    }
    __syncthreads();
    #pragma unroll
    for (int mt = 0; mt < 2; ++mt) {
      int row = wm * 32 + mt * 16 + c;
      int tok = row & 63;
      if ((row >> 6) == wi && tok < NWIN) {
        #pragma unroll
        for (int kg = 0; kg < 12; ++kg)
          areg[mt][kg] = *(const bf16x8*)&wb[tok * 384 + kg * 32 + g * 8];
      }
    }
    __syncthreads();
  }
  stage_qkv(0, 0, 0);
  stage_qkv(0, 1, 1);
  __syncthreads();

  // ================= per-head loop =================
  for (int h = 0; h < HEADS; ++h) {
    f32x4 acc[2][3] = {};
    const int par = h & 1;

    compute_qkv(0, par, acc);
    __syncthreads();
    stage_qkv(h, 2, par);

    compute_qkv(1, par ^ 1, acc);
    __syncthreads();
    if (h < 11) stage_qkv(h + 1, 0, par ^ 1);

    compute_qkv(2, par, acc);
    __syncthreads();
    if (h < 11) stage_qkv(h + 1, 1, par);

    // epilogue: scatter q, k, v^T into per-window buffers
    {
      int winE = wm >> 1;
      ushort* qsE = smem + QS_OFF + winE * 2432;
      ushort* ksE = smem + KS_OFF + winE * 2432;
      ushort* vtE = smem + VT_OFF + winE * 2368;
      #pragma unroll
      for (int nt = 0; nt < 3; ++nt) {
        int gnt = wn * 3 + nt;
        int which = gnt >> 1;
        int d = (gnt & 1) * 16 + c;
        float qb_ = qbF[which * 384 + h * 32 + d];
        #pragma unroll
        for (int mt = 0; mt < 2; ++mt) {
          #pragma unroll
          for (int r = 0; r < 4; ++r) {
            int tok = (wm & 1) * 32 + mt * 16 + g * 4 + r;
            float v = acc[mt][nt][r] + qb_;
            if (which == 0)      qsE[tok * 38 + d] = f2bf(v);
            else if (which == 1) ksE[tok * 38 + d] = f2bf(v);
            else                 vtE[d * 74 + tok] = f2bf(v);
          }
        }
      }
    }
    __syncthreads();

    // ---- attention: wave handles (win, q-tile wq)
    ushort* qsw = smem + QS_OFF + win * 2432;
    ushort* ksw = smem + KS_OFF + win * 2432;
    ushort* vtw = smem + VT_OFF + win * 2368;
    const int wdx = ((blk << 1) + win) & 63;
    const f32x4* bw4 = (const f32x4*)(bmF + ((((size_t)(wdx * HEADS + h)) * 4 + wq) * 4 * 64 + l) * 4);
    f32x4 bmv[4];
    #pragma unroll
    for (int kt = 0; kt < 4; ++kt) bmv[kt] = bw4[kt * 64];

    f32x4 sacc[4] = {};
    {
      bf16x8 aq = *(const bf16x8*)&qsw[(wq * 16 + c) * 38 + g * 8];
      #pragma unroll
      for (int kt = 0; kt < 4; ++kt) {
        bf16x8 bk = *(const bf16x8*)&ksw[(kt * 16 + c) * 38 + g * 8];
        sacc[kt] = __builtin_amdgcn_mfma_f32_16x16x32_bf16(aq, bk, sacc[kt], 0, 0, 0);
      }
    }
    float p[4][4];
    #pragma unroll
    for (int r = 0; r < 4; ++r) {
      float s0 = sacc[0][r] + bmv[0][r], s1 = sacc[1][r] + bmv[1][r];
      float s2 = sacc[2][r] + bmv[2][r], s3 = sacc[3][r] + bmv[3][r];
      float mx = fmaxf(fmaxf(s0, s1), fmaxf(s2, s3));
      mx = fmaxf(mx, __shfl_xor(mx, 1, 64));
      mx = fmaxf(mx, __shfl_xor(mx, 2, 64));
      mx = fmaxf(mx, __shfl_xor(mx, 4, 64));
      mx = fmaxf(mx, __shfl_xor(mx, 8, 64));
      float p0 = __builtin_exp2f((s0 - mx) * LOG2E);
      float p1 = __builtin_exp2f((s1 - mx) * LOG2E);
      float p2 = __builtin_exp2f((s2 - mx) * LOG2E);
      float p3 = __builtin_exp2f((s3 - mx) * LOG2E);
      float sum = p0 + p1 + p2 + p3;
      sum += __shfl_xor(sum, 1, 64);
      sum += __shfl_xor(sum, 2, 64);
      sum += __shfl_xor(sum, 4, 64);
      sum += __shfl_xor(sum, 8, 64);
      float inv = 1.0f / sum;
      p[0][r] = p0 * inv; p[1][r] = p1 * inv; p[2][r] = p2 * inv; p[3][r] = p3 * inv;
    }
    // PV via P staged in own qs rows (wave-private rows of this window)
    f32x4 pacc[2] = {};
    #pragma unroll
    for (int kkh = 0; kkh < 2; ++kkh) {
      #pragma unroll
      for (int t = 0; t < 2; ++t) {
        int kt = kkh * 2 + t;
        #pragma unroll
        for (int r = 0; r < 4; ++r)
          qsw[(wq * 16 + g * 4 + r) * 38 + t * 16 + c] = f2bf(p[kt][r]);
      }
      bf16x8 ap = *(const bf16x8*)&qsw[(wq * 16 + c) * 38 + g * 8];
      #pragma unroll
      for (int dt = 0; dt < 2; ++dt) {
        bf16x8 bv = *(const bf16x8*)&vtw[(dt * 16 + c) * 74 + kkh * 32 + g * 8];
        pacc[dt] = __builtin_amdgcn_mfma_f32_16x16x32_bf16(ap, bv, pacc[dt], 0, 0, 0);
      }
    }
    // attn-out -> global bf16 [window][tok][384]
    #pragma unroll
    for (int dt = 0; dt < 2; ++dt) {
      #pragma unroll
      for (int rr = 0; rr < 4; ++rr) {
        int tok = wq * 16 + g * 4 + rr;
        if (tok < NWIN)
          aog[((size_t)((blk << 1) + win) * NWIN + tok) * DIM + h * 32 + dt * 16 + c] =
              f2bf(pacc[dt][rr]);
      }
    }
    __syncthreads();                  // attention reads done before next epilogue
  }
}

// ===================== kernel 3: proj GEMM 128x128, K=384 (unchanged, verified) ============
__global__ __launch_bounds__(256, 2) void proj_kernel(
    const ushort* __restrict__ ao, const ushort* __restrict__ wpb,
    const float* __restrict__ proj_b, float* __restrict__ out)
{
  extern __shared__ ushort sm3[];
  ushort* lA = sm3;                  // 2 x [128][64]
  ushort* lB = sm3 + 16384;          // 2 x [128][64]

  const int blk = blockIdx.x;
  const int bM = blk / 3, bN = blk - bM * 3;
  const int m0 = bM * 128, n0 = bN * 128;
  const int tid = threadIdx.x;
  const int w = tid >> 6, l = tid & 63;
  const int c = l & 15, g = l >> 4;
  const int wm = w >> 1, wn = w & 1;   // wave tile 64 x 64

  auto stageA = [&](int kc, int buf) {
    #pragma unroll
    for (int s = 0; s < 4; ++s) {
      int i = s * 256 + tid;
      int row = i >> 3, g16 = i & 7;
      gload16(ao + (size_t)(m0 + row) * DIM + kc * 64 + ((g16 ^ (row & 7)) << 3),
              lA + buf * 8192 + i * 8);
    }
  };
  auto stageB = [&](int kc, int buf) {
    #pragma unroll
    for (int s = 0; s < 4; ++s) {
      int i = s * 256 + tid;
      int row = i >> 3, g16 = i & 7;
      gload16(wpb + (size_t)(n0 + row) * DIM + kc * 64 + ((g16 ^ (row & 7)) << 3),
              lB + buf * 8192 + i * 8);
    }
  };

  f32x4 acc[4][4] = {};
  stageA(0, 0); stageB(0, 0);
  stageA(1, 1); stageB(1, 1);
  __syncthreads();

  for (int kc = 0; kc < 6; ++kc) {
    const ushort* A = lA + (kc & 1) * 8192;
    const ushort* B = lB + (kc & 1) * 8192;
    #pragma unroll
    for (int kk = 0; kk < 2; ++kk) {
      int swz = ((kk * 4 + g) ^ (c & 7)) << 3;
      bf16x8 af[4], bfr[4];
      #pragma unroll
      for (int mt = 0; mt < 4; ++mt)
        af[mt] = *(const bf16x8*)&A[(wm * 64 + mt * 16 + c) * 64 + swz];
      #pragma unroll
      for (int nt = 0; nt < 4; ++nt)
        bfr[nt] = *(const bf16x8*)&B[(wn * 64 + nt * 16 + c) * 64 + swz];
      #pragma unroll
      for (int mt = 0; mt < 4; ++mt)
        #pragma unroll
        for (int nt = 0; nt < 4; ++nt)
          acc[mt][nt] = __builtin_amdgcn_mfma_f32_16x16x32_bf16(af[mt], bfr[nt], acc[mt][nt], 0, 0, 0);
    }
    __syncthreads();
    if (kc + 2 < 6) { stageA(kc + 2, kc & 1); stageB(kc + 2, kc & 1); }
  }

  #pragma unroll
  for (int nt = 0; nt < 4; ++nt) {
    int col = n0 + wn * 64 + nt * 16 + c;
    float pb = proj_b[col];
    #pragma unroll
    for (int mt = 0; mt < 4; ++mt) {
      #pragma unroll
      for (int r = 0; r < 4; ++r) {
        int row = m0 + wm * 64 + mt * 16 + g * 4 + r;
        out[(size_t)row * DIM + col] = acc[mt][nt][r] + pb;
      }
    }
  }
}

// ===================== fallback: EXACT r5-passed monolith + bmF bias (unchanged) ==========
#define FWB_OFF 0
#define FQS_OFF 24576
#define FKS_OFF 29696
#define FVT_OFF 34816
#define FAO_OFF 39424
#define FSMEM_US 77056   // 154112 bytes

__global__ __launch_bounds__(512, 2) void winattn_fused(
    const float* __restrict__ x, const float* __restrict__ qbF,
    const float* __restrict__ proj_b, const ushort* __restrict__ wqb,
    const ushort* __restrict__ wpb, const float* __restrict__ bmF,
    float* __restrict__ out)
{
  extern __shared__ ushort smem[];
  ushort* wb = smem + FWB_OFF;
  ushort* ao = smem + FAO_OFF;

  const int blk = blockIdx.x;
  const int tid = threadIdx.x;
  const int w = tid >> 6, l = tid & 63;
  const int c = l & 15, g = l >> 4;
  const int wm = w >> 1, wn = w & 1;
  const int win = w >> 2, wq = w & 3;
  const float LOG2E = 1.4426950408889634f;

  ushort* qsw = smem + FQS_OFF + win * 2560;
  ushort* ksw = smem + FKS_OFF + win * 2560;
  ushort* vtw = smem + FVT_OFF + win * 2304;
  ushort* psw = qsw;

  auto stage_qkv = [&](int h, int kc, int buf) {
    #pragma unroll
    for (int s = 0; s < 3; ++s) {
      int i = s * 512 + tid;
      int n = i >> 4, g16 = i & 15;
      int grow = (n >> 5) * 384 + h * 32 + (n & 31);
      int sg = (g16 & 8) | ((g16 & 7) ^ (n & 7));
      gload16(wqb + (size_t)grow * DIM + kc * 128 + (sg << 3), wb + buf * 12288 + i * 8);
    }
  };
  auto stage_proj = [&](int nb, int kc, int buf) {
    #pragma unroll
    for (int s = 0; s < 3; ++s) {
      int i = s * 512 + tid;
      int n = i >> 4, g16 = i & 15;
      int grow = nb * 96 + n;
      int sg = (g16 & 8) | ((g16 & 7) ^ (n & 7));
      gload16(wpb + (size_t)grow * DIM + kc * 128 + (sg << 3), wb + buf * 12288 + i * 8);
    }
  };

  bf16x8 areg[2][12] = {};
  auto compute_qkv = [&](int kcC, int buf, f32x4 (&acc)[2][3]) {
    const ushort* wcb = wb + buf * 12288;
    #pragma unroll
    for (int kk = 0; kk < 4; ++kk) {
      int sB = ((kk * 4 + g) ^ (c & 7)) << 3;
      #pragma unroll
      for (int nt = 0; nt < 3; ++nt) {
        int n = (wn * 3 + nt) * 16 + c;
        bf16x8 bb = *(const bf16x8*)&wcb[n * 128 + sB];
        acc[0][nt] = __builtin_amdgcn_mfma_f32_16x16x32_bf16(areg[0][kcC * 4 + kk], bb, acc[0][nt], 0, 0, 0);
        acc[1][nt] = __builtin_amdgcn_mfma_f32_16x16x32_bf16(areg[1][kcC * 4 + kk], bb, acc[1][nt], 0, 0, 0);
      }
    }
  };
  auto compute_proj = [&](int kcC, int buf, f32x4 (&acc)[2][3]) {
    const ushort* wcb = wb + buf * 12288;
    int r0 = wm * 32 + c;      if (r0 >= 98) r0 -= 64;
    int r1 = wm * 32 + 16 + c; if (r1 >= 98) r1 -= 64;
    #pragma unroll
    for (int kk = 0; kk < 4; ++kk) {
      int p = kcC * 16 + kk * 4 + g;
      int sw = (p ^ (c & 7)) << 3;
      bf16x8 a0 = *(const bf16x8*)&ao[r0 * 384 + sw];
      bf16x8 a1 = *(const bf16x8*)&ao[r1 * 384 + sw];
      int sB = ((kk * 4 + g) ^ (c & 7)) << 3;
      #pragma unroll
      for (int nt = 0; nt < 3; ++nt) {
        int n = (wn * 3 + nt) * 16 + c;
        bf16x8 bb = *(const bf16x8*)&wcb[n * 128 + sB];
        acc[0][nt] = __builtin_amdgcn_mfma_f32_16x16x32_bf16(a0, bb, acc[0][nt], 0, 0, 0);
        acc[1][nt] = __builtin_amdgcn_mfma_f32_16x16x32_bf16(a1, bb, acc[1][nt], 0, 0, 0);
      }
    }
  };

  stage_qkv(0, 0, 0);
  stage_qkv(0, 1, 1);
  {
    const float* xb = x + (size_t)blk * (2 * NWIN * DIM);
    for (int i = tid; i < 9408; i += 512) {
      float4 f = ((const float4*)xb)[i];
      int row = i / 96, c4 = i - row * 96;
      int k = c4 * 4;
      int gr = k >> 3;
      u16x4 v4 = { f2bf(f.x), f2bf(f.y), f2bf(f.z), f2bf(f.w) };
      *(u16x4*)&ao[row * 384 + ((gr ^ (row & 7)) << 3) + (k & 7)] = v4;
    }
  }
  __syncthreads();
  #pragma unroll
  for (int mt = 0; mt < 2; ++mt) {
    int row = wm * 32 + mt * 16 + c;
    int wi = row >> 6, tok = row & 63;
    if (tok < NWIN) {
      int ar = wi * 49 + tok;
      #pragma unroll
      for (int kg = 0; kg < 12; ++kg)
        areg[mt][kg] = *(const bf16x8*)&ao[ar * 384 + (((kg * 4 + g) ^ (ar & 7)) << 3)];
    }
  }

  for (int h = 0; h < HEADS; ++h) {
    f32x4 acc[2][3] = {};
    const int par = h & 1;
    compute_qkv(0, par, acc);
    __syncthreads();
    stage_qkv(h, 2, par);
    compute_qkv(1, par ^ 1, acc);
    __syncthreads();
    if (h < 11) stage_qkv(h + 1, 0, par ^ 1); else stage_proj(0, 0, par ^ 1);
    compute_qkv(2, par, acc);
    __syncthreads();
    if (h < 11) stage_qkv(h + 1, 1, par); else stage_proj(0, 1, par);
    {
      int winE = wm >> 1;
      ushort* qsE = smem + FQS_OFF + winE * 2560;
      ushort* ksE = smem + FKS_OFF + winE * 2560;
      ushort* vtE = smem + FVT_OFF + winE * 2304;
      #pragma unroll
      for (int nt = 0; nt < 3; ++nt) {
        int gnt = wn * 3 + nt;
        int which = gnt >> 1;
        int d = (gnt & 1) * 16 + c;
        float qb_ = qbF[which * 384 + h * 32 + d];
        #pragma unroll
        for (int mt = 0; mt < 2; ++mt) {
          #pragma unroll
          for (int r = 0; r < 4; ++r) {
            int tok = (wm & 1) * 32 + mt * 16 + g * 4 + r;
            float v = acc[mt][nt][r] + qb_;
            if (which == 0)      qsE[tok * 40 + d] = f2bf(v);
            else if (which == 1) ksE[tok * 40 + d] = f2bf(v);
            else                 vtE[d * 72 + tok] = f2bf(v);
          }
        }
      }
    }
    __syncthreads();

    const int wdx = ((blk << 1) + win) & 63;
    const f32x4* bw4 = (const f32x4*)(bmF + ((((size_t)(wdx * HEADS + h)) * 4 + wq) * 4 * 64 + l) * 4);
    f32x4 bmv[4];
    #pragma unroll
    for (int kt = 0; kt < 4; ++kt) bmv[kt] = bw4[kt * 64];

    f32x4 sacc[4] = {};
    {
      bf16x8 aq = *(const bf16x8*)&qsw[(wq * 16 + c) * 40 + g * 8];
      #pragma unroll
      for (int kt = 0; kt < 4; ++kt) {
        bf16x8 bk = *(const bf16x8*)&ksw[(kt * 16 + c) * 40 + g * 8];
        sacc[kt] = __builtin_amdgcn_mfma_f32_16x16x32_bf16(aq, bk, sacc[kt], 0, 0, 0);
      }
    }
    float p[4][4];
    #pragma unroll
    for (int r = 0; r < 4; ++r) {
      float s0 = sacc[0][r] + bmv[0][r], s1 = sacc[1][r] + bmv[1][r];
      float s2 = sacc[2][r] + bmv[2][r], s3 = sacc[3][r] + bmv[3][r];
      float mx = fmaxf(fmaxf(s0, s1), fmaxf(s2, s3));
      mx = fmaxf(mx, __shfl_xor(mx, 1, 64));
      mx = fmaxf(mx, __shfl_xor(mx, 2, 64));
      mx = fmaxf(mx, __shfl_xor(mx, 4, 64));
      mx = fmaxf(mx, __shfl_xor(mx, 8, 64));
      float p0 = __builtin_exp2f((s0 - mx) * LOG2E);
      float p1 = __builtin_exp2f((s1 - mx) * LOG2E);
      float p2 = __builtin_exp2f((s2 - mx) * LOG2E);
      float p3 = __builtin_exp2f((s3 - mx) * LOG2E);
      float sum = p0 + p1 + p2 + p3;
      sum += __shfl_xor(sum, 1, 64);
      sum += __shfl_xor(sum, 2, 64);
      sum += __shfl_xor(sum, 4, 64);
      sum += __shfl_xor(sum, 8, 64);
      float inv = 1.0f / sum;
      p[0][r] = p0 * inv; p[1][r] = p1 * inv; p[2][r] = p2 * inv; p[3][r] = p3 * inv;
    }
    f32x4 pacc2[2] = {};
    #pragma unroll
    for (int kkh = 0; kkh < 2; ++kkh) {
      #pragma unroll
      for (int t = 0; t < 2; ++t) {
        int kt = kkh * 2 + t;
        #pragma unroll
        for (int r = 0; r < 4; ++r)
          psw[(wq * 16 + g * 4 + r) * 40 + t * 16 + c] = f2bf(p[kt][r]);
      }
      bf16x8 ap = *(const bf16x8*)&psw[(wq * 16 + c) * 40 + g * 8];
      #pragma unroll
      for (int dt = 0; dt < 2; ++dt) {
        bf16x8 bv = *(const bf16x8*)&vtw[(dt * 16 + c) * 72 + kkh * 32 + g * 8];
        pacc2[dt] = __builtin_amdgcn_mfma_f32_16x16x32_bf16(ap, bv, pacc2[dt], 0, 0, 0);
      }
    }
    #pragma unroll
    for (int dt = 0; dt < 2; ++dt) {
      int gr0 = h * 4 + dt * 2 + (c >> 3);
      #pragma unroll
      for (int rr = 0; rr < 4; ++rr) {
        int tok = wq * 16 + g * 4 + rr;
        int row0 = win * 49 + tok;
        if (tok < NWIN)
          ao[row0 * 384 + (((gr0 ^ (row0 & 7)) << 3) | (c & 7))] = f2bf(pacc2[dt][rr]);
      }
    }
    __syncthreads();
  }

  __syncthreads();
  for (int nb = 0; nb < 4; ++nb) {
    f32x4 acc[2][3] = {};
    const int pb0 = (nb * 3) & 1;
    compute_proj(0, pb0, acc);
    __syncthreads();
    stage_proj(nb, 2, pb0);
    compute_proj(1, pb0 ^ 1, acc);
    __syncthreads();
    if (nb < 3) stage_proj(nb + 1, 0, pb0 ^ 1);
    compute_proj(2, pb0, acc);
    __syncthreads();
    if (nb < 3) stage_proj(nb + 1, 1, pb0);
    #pragma unroll
    for (int nt = 0; nt < 3; ++nt) {
      int col = nb * 96 + (wn * 3 + nt) * 16 + c;
      float pb = proj_b[col];
      #pragma unroll
      for (int mt = 0; mt < 2; ++mt) {
        #pragma unroll
        for (int r = 0; r < 4; ++r) {
          int mrow = wm * 32 + mt * 16 + g * 4 + r;
          if (mrow < 98) {
            int wi = mrow >= NWIN;
            int tok = mrow - (wi ? NWIN : 0);
            out[((size_t)((blk << 1) + wi) * NWIN + tok) * DIM + col] = acc[mt][nt][r] + pb;
          }
        }
      }
    }
  }
}

extern "C" void kernel_launch(void* const* d_in, const int* in_sizes, int n_in,
                              void* d_out, int out_size, void* d_ws, size_t ws_size,
                              hipStream_t stream) {
  const float* x          = (const float*)d_in[0];
  const float* mask       = (const float*)d_in[1];
  const float* bias_table = (const float*)d_in[2];
  const float* qkv_w      = (const float*)d_in[3];
  const float* qkv_b      = (const float*)d_in[4];
  const float* proj_w     = (const float*)d_in[5];
  const float* proj_b     = (const float*)d_in[6];
  const int*   rel_index  = (const int*)d_in[7];
  float* out = (float*)d_out;

  // ws: wqb @0 | wpb @884736 | qbF @1179648 | bmF @1184256 | aog @13767168 (154140672 B)
  ushort* wqb = (ushort*)d_ws;
  ushort* wpb = (ushort*)((char*)d_ws + 884736);
  float*  qbF = (float*)((char*)d_ws + 1179648);
  float*  bmF = (float*)((char*)d_ws + 1184256);
  ushort* aog = (ushort*)((char*)d_ws + 13767168);
  const size_t NEED = 13767168ull + 154140672ull;

  prep_kernel<<<1024, 256, 0, stream>>>(qkv_w, proj_w, bias_table, rel_index, mask, qkv_b,
                                        wqb, wpb, qbF, bmF);

  if (ws_size >= NEED) {
    hipFuncSetAttribute((const void*)qkv_attn_kernel,
                        hipFuncAttributeMaxDynamicSharedMemorySize, SMEM2_US * 2);
    qkv_attn_kernel<<<2048, 512, SMEM2_US * 2, stream>>>(x, qbF, wqb, bmF, aog);
    hipFuncSetAttribute((const void*)proj_kernel,
                        hipFuncAttributeMaxDynamicSharedMemorySize, 65536);
    proj_kernel<<<4704, 256, 65536, stream>>>(aog, wpb, proj_b, out);
  } else {
    hipFuncSetAttribute((const void*)winattn_fused,
                        hipFuncAttributeMaxDynamicSharedMemorySize, FSMEM_US * 2);
    winattn_fused<<<2048, 512, FSMEM_US * 2, stream>>>(x, qbF, proj_b, wqb, wpb, bmF, out);
  }
}

// Round 10
// 929.677 us; speedup vs baseline: 1.0085x; 1.0085x over previous
//
#include <hip/hip_runtime.h>
#include <hip/hip_bf16.h>

#define DIM   384
#define NWIN  49
#define HEADS 12
#define SCALE 0.17677669529663687f

typedef unsigned short ushort;
using bf16x8 = __attribute__((ext_vector_type(8))) short;
using u16x4  = __attribute__((ext_vector_type(4))) ushort;
using f32x4  = __attribute__((ext_vector_type(4))) float;

__device__ __forceinline__ ushort f2bf(float f) {
  unsigned u = __float_as_uint(f);
  u += 0x7fff + ((u >> 16) & 1);          // RNE
  return (ushort)(u >> 16);
}

typedef __attribute__((address_space(1))) const void gas_void;
typedef __attribute__((address_space(3))) void las_void;

__device__ __forceinline__ void gload16(const ushort* g, ushort* l) {
  __builtin_amdgcn_global_load_lds((gas_void*)g, (las_void*)l, 16, 0, 0);
}

// ===================== prep (verbatim r8) =====================
__global__ void prep_kernel(const float* __restrict__ qkv_w, const float* __restrict__ proj_w,
                            const float* __restrict__ bias_table, const int* __restrict__ rel_index,
                            const float* __restrict__ mask, const float* __restrict__ qkv_b,
                            ushort* __restrict__ wqb, ushort* __restrict__ wpb,
                            float* __restrict__ qbF, float* __restrict__ bmF) {
  int i0 = blockIdx.x * 256 + threadIdx.x;
  int stride = gridDim.x * 256;
  for (int i = i0; i < 1152 * 384; i += stride) {
    float v = qkv_w[i];
    if (i < 384 * 384) v *= SCALE;                 // fold softmax scale into Wq
    wqb[i] = f2bf(v);
  }
  for (int i = i0; i < 384 * 384; i += stride) wpb[i] = f2bf(proj_w[i]);
  for (int i = i0; i < 1152; i += stride) qbF[i] = qkv_b[i] * (i < 384 ? SCALE : 1.f);
  for (int i = i0; i < 64 * HEADS * 4 * 4 * 64 * 4; i += stride) {
    int r = i & 3, lane = (i >> 2) & 63, kt = (i >> 8) & 3, wq = (i >> 10) & 3;
    int hw = i >> 12;
    int h = hw % HEADS, wdx = hw / HEADS;
    int q = wq * 16 + (lane >> 4) * 4 + r;
    int key = kt * 16 + (lane & 15);
    float v;
    if (q < NWIN)
      v = (key < NWIN) ? bias_table[rel_index[q * NWIN + key] * HEADS + h]
                         + mask[wdx * (NWIN * NWIN) + q * NWIN + key]
                       : -3.0e38f;
    else
      v = 0.f;
    bmF[i] = v;
  }
}

// ============ kernel A: QKV mega-GEMM  M=200704 N=1152 K=384 (proj template) ============
// out layout: {q,k,v}g[((win*12+h)*49+tok)*32 + d], bf16, bias added, q pre-scaled.
__global__ __launch_bounds__(256) void qkv_gemm_kernel(
    const float* __restrict__ x, const float* __restrict__ qbF,
    const ushort* __restrict__ wqb,
    ushort* __restrict__ qg, ushort* __restrict__ kg, ushort* __restrict__ vg)
{
  extern __shared__ ushort smA[];
  ushort* lA = smA;                  // 2 x [128][64]
  ushort* lB = smA + 16384;          // 2 x [128][64]

  const int blk = blockIdx.x;
  const int bM = blk / 9, bN = blk - bM * 9;
  const int m0 = bM * 128, n0 = bN * 128;
  const int which = bN / 3;                    // 0=q 1=k 2=v (128 | 384)
  ushort* outw = which == 0 ? qg : (which == 1 ? kg : vg);
  const int tid = threadIdx.x;
  const int w = tid >> 6, l = tid & 63;
  const int c = l & 15, g = l >> 4;
  const int wm = w >> 1, wn = w & 1;           // wave tile 64 x 64

  auto stageA = [&](int kc, int buf) {         // fp32 x -> bf16, src-swizzled LDS write
    #pragma unroll
    for (int s = 0; s < 4; ++s) {
      int i = s * 256 + tid;                   // 1024 granules of 8
      int row = i >> 3, gc = i & 7;
      const float4* src = (const float4*)(x + (size_t)(m0 + row) * DIM + kc * 64 + gc * 8);
      float4 f0 = src[0], f1 = src[1];
      ushort tmp[8] = { f2bf(f0.x), f2bf(f0.y), f2bf(f0.z), f2bf(f0.w),
                        f2bf(f1.x), f2bf(f1.y), f2bf(f1.z), f2bf(f1.w) };
      *(bf16x8*)&lA[buf * 8192 + row * 64 + ((gc ^ (row & 7)) << 3)] = *(bf16x8*)tmp;
    }
  };
  auto stageB = [&](int kc, int buf) {
    #pragma unroll
    for (int s = 0; s < 4; ++s) {
      int i = s * 256 + tid;
      int row = i >> 3, gc = i & 7;
      gload16(wqb + (size_t)(n0 + row) * DIM + kc * 64 + ((gc ^ (row & 7)) << 3),
              lB + buf * 8192 + i * 8);
    }
  };

  f32x4 acc[4][4] = {};
  stageA(0, 0); stageB(0, 0);
  stageA(1, 1); stageB(1, 1);
  __syncthreads();

  for (int kc = 0; kc < 6; ++kc) {
    const ushort* A = lA + (kc & 1) * 8192;
    const ushort* B = lB + (kc & 1) * 8192;
    #pragma unroll
    for (int kk = 0; kk < 2; ++kk) {
      int swz = ((kk * 4 + g) ^ (c & 7)) << 3;
      bf16x8 af[4], bfr[4];
      #pragma unroll
      for (int mt = 0; mt < 4; ++mt)
        af[mt] = *(const bf16x8*)&A[(wm * 64 + mt * 16 + c) * 64 + swz];
      #pragma unroll
      for (int nt = 0; nt < 4; ++nt)
        bfr[nt] = *(const bf16x8*)&B[(wn * 64 + nt * 16 + c) * 64 + swz];
      #pragma unroll
      for (int mt = 0; mt < 4; ++mt)
        #pragma unroll
        for (int nt = 0; nt < 4; ++nt)
          acc[mt][nt] = __builtin_amdgcn_mfma_f32_16x16x32_bf16(af[mt], bfr[nt], acc[mt][nt], 0, 0, 0);
    }
    __syncthreads();
    if (kc + 2 < 6) { stageA(kc + 2, kc & 1); stageB(kc + 2, kc & 1); }
  }

  #pragma unroll
  for (int nt = 0; nt < 4; ++nt) {
    int n = n0 + wn * 64 + nt * 16 + c;
    int h = (n - which * 384) >> 5;
    int d = n & 31;
    float qb_ = qbF[n];
    #pragma unroll
    for (int mt = 0; mt < 4; ++mt) {
      #pragma unroll
      for (int r = 0; r < 4; ++r) {
        int tok = m0 + wm * 64 + mt * 16 + g * 4 + r;
        int win = tok / 49;
        int tk = tok - win * 49;
        outw[((size_t)(win * HEADS + h) * NWIN + tk) * 32 + d] = f2bf(acc[mt][nt][r] + qb_);
      }
    }
  }
}

// ============ kernel B: barrier-free attention, 1 wave per (window, head) ============
#define VSTR 68
__global__ __launch_bounds__(256) void attn_kernel(
    const ushort* __restrict__ kg, const ushort* __restrict__ vg,
    const float* __restrict__ bmF, ushort* __restrict__ qg)
{
  __shared__ ushort vts[4][32 * VSTR];
  __shared__ ushort pbs[4][16 * 36];

  const int tid = threadIdx.x;
  const int w = tid >> 6, l = tid & 63;
  const int c = l & 15, g = l >> 4;
  const int task = blockIdx.x * 4 + w;
  const int win = task / 12, h = task - win * 12;
  const int wdx = win & 63;
  const float LOG2E = 1.4426950408889634f;

  const size_t sb = (size_t)(win * HEADS + h) * (NWIN * 32);
  ushort* qslice = qg + sb;                    // read q, then overwrite with attn-out
  const ushort* kb = kg + sb;
  const ushort* vb = vg + sb;
  ushort* vt = vts[w];
  ushort* pb = pbs[w];

  // q,k fragments: coalesced global -> regs (rows >=49 read garbage; masked later)
  bf16x8 qf[4], kf[4];
  #pragma unroll
  for (int t = 0; t < 4; ++t) {
    qf[t] = *(const bf16x8*)(qslice + (t * 16 + c) * 32 + g * 8);
    kf[t] = *(const bf16x8*)(kb + (t * 16 + c) * 32 + g * 8);
  }
  // v -> vT LDS (wave-private; within-wave lgkmcnt ordering, no barrier)
  #pragma unroll
  for (int it = 0; it < 25; ++it) {
    int i = it * 64 + l;
    if (i < NWIN * 32) vt[(i & 31) * VSTR + (i >> 5)] = vb[i];
  }
  for (int i = l; i < 32 * 15; i += 64) {      // zero keys 49..63
    int d = i / 15, t = NWIN + (i - d * 15);
    vt[d * VSTR + t] = 0;
  }

  const float* bmBase = bmF + (size_t)((wdx * HEADS + h) * 4) * 1024 + l * 4;

  #pragma unroll
  for (int qt = 0; qt < 4; ++qt) {
    f32x4 sacc[4] = {};
    #pragma unroll
    for (int kt = 0; kt < 4; ++kt)
      sacc[kt] = __builtin_amdgcn_mfma_f32_16x16x32_bf16(qf[qt], kf[kt], sacc[kt], 0, 0, 0);
    const f32x4* bw4 = (const f32x4*)(bmBase + qt * 1024);
    float p[4][4];
    {
      f32x4 b0 = bw4[0], b1 = bw4[64], b2 = bw4[128], b3 = bw4[192];
      #pragma unroll
      for (int r = 0; r < 4; ++r) {
        float s0 = sacc[0][r] + b0[r], s1 = sacc[1][r] + b1[r];
        float s2 = sacc[2][r] + b2[r], s3 = sacc[3][r] + b3[r];
        float mx = fmaxf(fmaxf(s0, s1), fmaxf(s2, s3));
        mx = fmaxf(mx, __shfl_xor(mx, 1, 64));
        mx = fmaxf(mx, __shfl_xor(mx, 2, 64));
        mx = fmaxf(mx, __shfl_xor(mx, 4, 64));
        mx = fmaxf(mx, __shfl_xor(mx, 8, 64));
        float p0 = __builtin_exp2f((s0 - mx) * LOG2E);
        float p1 = __builtin_exp2f((s1 - mx) * LOG2E);
        float p2 = __builtin_exp2f((s2 - mx) * LOG2E);
        float p3 = __builtin_exp2f((s3 - mx) * LOG2E);
        float sum = p0 + p1 + p2 + p3;
        sum += __shfl_xor(sum, 1, 64);
        sum += __shfl_xor(sum, 2, 64);
        sum += __shfl_xor(sum, 4, 64);
        sum += __shfl_xor(sum, 8, 64);
        float inv = 1.0f / sum;
        p[0][r] = p0 * inv; p[1][r] = p1 * inv; p[2][r] = p2 * inv; p[3][r] = p3 * inv;
      }
    }
    // PV in two 32-key halves through wave-private P buffer
    f32x4 pacc[2] = {};
    #pragma unroll
    for (int kkh = 0; kkh < 2; ++kkh) {
      #pragma unroll
      for (int t = 0; t < 2; ++t) {
        int kt = kkh * 2 + t;
        #pragma unroll
        for (int r = 0; r < 4; ++r)
          pb[(g * 4 + r) * 36 + t * 16 + c] = f2bf(p[kt][r]);
      }
      bf16x8 ap = *(const bf16x8*)&pb[c * 36 + g * 8];
      #pragma unroll
      for (int dt = 0; dt < 2; ++dt) {
        bf16x8 bv = *(const bf16x8*)&vt[(dt * 16 + c) * VSTR + kkh * 32 + g * 8];
        pacc[dt] = __builtin_amdgcn_mfma_f32_16x16x32_bf16(ap, bv, pacc[dt], 0, 0, 0);
      }
    }
    // attn-out overwrites own q slice (q already in regs)
    #pragma unroll
    for (int dt = 0; dt < 2; ++dt) {
      #pragma unroll
      for (int rr = 0; rr < 4; ++rr) {
        int tok = qt * 16 + g * 4 + rr;
        if (tok < NWIN)
          qslice[tok * 32 + dt * 16 + c] = f2bf(pacc[dt][rr]);
      }
    }
  }
}

// ============ kernel C: proj GEMM 128x128 K=384 (stageA gathers [win][h][tok][32]) =======
__global__ __launch_bounds__(256, 2) void proj_kernel(
    const ushort* __restrict__ ao, const ushort* __restrict__ wpb,
    const float* __restrict__ proj_b, float* __restrict__ out)
{
  extern __shared__ ushort sm3[];
  ushort* lA = sm3;                  // 2 x [128][64]
  ushort* lB = sm3 + 16384;          // 2 x [128][64]

  const int blk = blockIdx.x;
  const int bM = blk / 3, bN = blk - bM * 3;
  const int m0 = bM * 128, n0 = bN * 128;
  const int tid = threadIdx.x;
  const int w = tid >> 6, l = tid & 63;
  const int c = l & 15, g = l >> 4;
  const int wm = w >> 1, wn = w & 1;   // wave tile 64 x 64

  auto stageA = [&](int kc, int buf) {
    #pragma unroll
    for (int s = 0; s < 4; ++s) {
      int i = s * 256 + tid;
      int row = i >> 3, gc = i & 7;
      int tok = m0 + row;
      int win = tok / 49;
      int tk = tok - win * 49;
      int sg = gc ^ (row & 7);
      int kfull = kc * 64 + sg * 8;
      gload16(ao + ((size_t)(win * HEADS + (kfull >> 5)) * NWIN + tk) * 32 + (kfull & 31),
              lA + buf * 8192 + i * 8);
    }
  };
  auto stageB = [&](int kc, int buf) {
    #pragma unroll
    for (int s = 0; s < 4; ++s) {
      int i = s * 256 + tid;
      int row = i >> 3, gc = i & 7;
      gload16(wpb + (size_t)(n0 + row) * DIM + kc * 64 + ((gc ^ (row & 7)) << 3),
              lB + buf * 8192 + i * 8);
    }
  };

  f32x4 acc[4][4] = {};
  stageA(0, 0); stageB(0, 0);
  stageA(1, 1); stageB(1, 1);
  __syncthreads();

  for (int kc = 0; kc < 6; ++kc) {
    const ushort* A = lA + (kc & 1) * 8192;
    const ushort* B = lB + (kc & 1) * 8192;
    #pragma unroll
    for (int kk = 0; kk < 2; ++kk) {
      int swz = ((kk * 4 + g) ^ (c & 7)) << 3;
      bf16x8 af[4], bfr[4];
      #pragma unroll
      for (int mt = 0; mt < 4; ++mt)
        af[mt] = *(const bf16x8*)&A[(wm * 64 + mt * 16 + c) * 64 + swz];
      #pragma unroll
      for (int nt = 0; nt < 4; ++nt)
        bfr[nt] = *(const bf16x8*)&B[(wn * 64 + nt * 16 + c) * 64 + swz];
      #pragma unroll
      for (int mt = 0; mt < 4; ++mt)
        #pragma unroll
        for (int nt = 0; nt < 4; ++nt)
          acc[mt][nt] = __builtin_amdgcn_mfma_f32_16x16x32_bf16(af[mt], bfr[nt], acc[mt][nt], 0, 0, 0);
    }
    __syncthreads();
    if (kc + 2 < 6) { stageA(kc + 2, kc & 1); stageB(kc + 2, kc & 1); }
  }

  #pragma unroll
  for (int nt = 0; nt < 4; ++nt) {
    int col = n0 + wn * 64 + nt * 16 + c;
    float pb = proj_b[col];
    #pragma unroll
    for (int mt = 0; mt < 4; ++mt) {
      #pragma unroll
      for (int r = 0; r < 4; ++r) {
        int row = m0 + wm * 64 + mt * 16 + g * 4 + r;
        out[(size_t)row * DIM + col] = acc[mt][nt][r] + pb;
      }
    }
  }
}

// ===================== fallback: EXACT r8 monolith (verbatim) =====================
#define FWB_OFF 0
#define FQS_OFF 24576
#define FKS_OFF 29696
#define FVT_OFF 34816
#define FAO_OFF 39424
#define FSMEM_US 77056   // 154112 bytes

__global__ __launch_bounds__(512, 2) void winattn_fused(
    const float* __restrict__ x, const float* __restrict__ qbF,
    const float* __restrict__ proj_b, const ushort* __restrict__ wqb,
    const ushort* __restrict__ wpb, const float* __restrict__ bmF,
    float* __restrict__ out)
{
  extern __shared__ ushort smem[];
  ushort* wb = smem + FWB_OFF;
  ushort* ao = smem + FAO_OFF;

  const int blk = blockIdx.x;
  const int tid = threadIdx.x;
  const int w = tid >> 6, l = tid & 63;
  const int c = l & 15, g = l >> 4;
  const int wm = w >> 1, wn = w & 1;
  const int win = w >> 2, wq = w & 3;
  const float LOG2E = 1.4426950408889634f;

  ushort* qsw = smem + FQS_OFF + win * 2560;
  ushort* ksw = smem + FKS_OFF + win * 2560;
  ushort* vtw = smem + FVT_OFF + win * 2304;
  ushort* psw = qsw;

  auto stage_qkv = [&](int h, int kc, int buf) {
    #pragma unroll
    for (int s = 0; s < 3; ++s) {
      int i = s * 512 + tid;
      int n = i >> 4, g16 = i & 15;
      int grow = (n >> 5) * 384 + h * 32 + (n & 31);
      int sg = (g16 & 8) | ((g16 & 7) ^ (n & 7));
      gload16(wqb + (size_t)grow * DIM + kc * 128 + (sg << 3), wb + buf * 12288 + i * 8);
    }
  };
  auto stage_proj = [&](int nb, int kc, int buf) {
    #pragma unroll
    for (int s = 0; s < 3; ++s) {
      int i = s * 512 + tid;
      int n = i >> 4, g16 = i & 15;
      int grow = nb * 96 + n;
      int sg = (g16 & 8) | ((g16 & 7) ^ (n & 7));
      gload16(wpb + (size_t)grow * DIM + kc * 128 + (sg << 3), wb + buf * 12288 + i * 8);
    }
  };

  bf16x8 areg[2][12] = {};
  auto compute_qkv = [&](int kcC, int buf, f32x4 (&acc)[2][3]) {
    const ushort* wcb = wb + buf * 12288;
    #pragma unroll
    for (int kk = 0; kk < 4; ++kk) {
      int sB = ((kk * 4 + g) ^ (c & 7)) << 3;
      #pragma unroll
      for (int nt = 0; nt < 3; ++nt) {
        int n = (wn * 3 + nt) * 16 + c;
        bf16x8 bb = *(const bf16x8*)&wcb[n * 128 + sB];
        acc[0][nt] = __builtin_amdgcn_mfma_f32_16x16x32_bf16(areg[0][kcC * 4 + kk], bb, acc[0][nt], 0, 0, 0);
        acc[1][nt] = __builtin_amdgcn_mfma_f32_16x16x32_bf16(areg[1][kcC * 4 + kk], bb, acc[1][nt], 0, 0, 0);
      }
    }
  };
  auto compute_proj = [&](int kcC, int buf, f32x4 (&acc)[2][3]) {
    const ushort* wcb = wb + buf * 12288;
    int r0 = wm * 32 + c;      if (r0 >= 98) r0 -= 64;
    int r1 = wm * 32 + 16 + c; if (r1 >= 98) r1 -= 64;
    #pragma unroll
    for (int kk = 0; kk < 4; ++kk) {
      int p = kcC * 16 + kk * 4 + g;
      int sw = (p ^ (c & 7)) << 3;
      bf16x8 a0 = *(const bf16x8*)&ao[r0 * 384 + sw];
      bf16x8 a1 = *(const bf16x8*)&ao[r1 * 384 + sw];
      int sB = ((kk * 4 + g) ^ (c & 7)) << 3;
      #pragma unroll
      for (int nt = 0; nt < 3; ++nt) {
        int n = (wn * 3 + nt) * 16 + c;
        bf16x8 bb = *(const bf16x8*)&wcb[n * 128 + sB];
        acc[0][nt] = __builtin_amdgcn_mfma_f32_16x16x32_bf16(a0, bb, acc[0][nt], 0, 0, 0);
        acc[1][nt] = __builtin_amdgcn_mfma_f32_16x16x32_bf16(a1, bb, acc[1][nt], 0, 0, 0);
      }
    }
  };

  stage_qkv(0, 0, 0);
  stage_qkv(0, 1, 1);
  {
    const float* xb = x + (size_t)blk * (2 * NWIN * DIM);
    for (int i = tid; i < 9408; i += 512) {
      float4 f = ((const float4*)xb)[i];
      int row = i / 96, c4 = i - row * 96;
      int k = c4 * 4;
      int gr = k >> 3;
      u16x4 v4 = { f2bf(f.x), f2bf(f.y), f2bf(f.z), f2bf(f.w) };
      *(u16x4*)&ao[row * 384 + ((gr ^ (row & 7)) << 3) + (k & 7)] = v4;
    }
  }
  __syncthreads();
  #pragma unroll
  for (int mt = 0; mt < 2; ++mt) {
    int row = wm * 32 + mt * 16 + c;
    int wi = row >> 6, tok = row & 63;
    if (tok < NWIN) {
      int ar = wi * 49 + tok;
      #pragma unroll
      for (int kg = 0; kg < 12; ++kg)
        areg[mt][kg] = *(const bf16x8*)&ao[ar * 384 + (((kg * 4 + g) ^ (ar & 7)) << 3)];
    }
  }

  for (int h = 0; h < HEADS; ++h) {
    f32x4 acc[2][3] = {};
    const int par = h & 1;
    compute_qkv(0, par, acc);
    __syncthreads();
    stage_qkv(h, 2, par);
    compute_qkv(1, par ^ 1, acc);
    __syncthreads();
    if (h < 11) stage_qkv(h + 1, 0, par ^ 1); else stage_proj(0, 0, par ^ 1);
    compute_qkv(2, par, acc);
    __syncthreads();
    if (h < 11) stage_qkv(h + 1, 1, par); else stage_proj(0, 1, par);
    {
      int winE = wm >> 1;
      ushort* qsE = smem + FQS_OFF + winE * 2560;
      ushort* ksE = smem + FKS_OFF + winE * 2560;
      ushort* vtE = smem + FVT_OFF + winE * 2304;
      #pragma unroll
      for (int nt = 0; nt < 3; ++nt) {
        int gnt = wn * 3 + nt;
        int which = gnt >> 1;
        int d = (gnt & 1) * 16 + c;
        float qb_ = qbF[which * 384 + h * 32 + d];
        #pragma unroll
        for (int mt = 0; mt < 2; ++mt) {
          #pragma unroll
          for (int r = 0; r < 4; ++r) {
            int tok = (wm & 1) * 32 + mt * 16 + g * 4 + r;
            float v = acc[mt][nt][r] + qb_;
            if (which == 0)      qsE[tok * 40 + d] = f2bf(v);
            else if (which == 1) ksE[tok * 40 + d] = f2bf(v);
            else                 vtE[d * 72 + tok] = f2bf(v);
          }
        }
      }
    }
    __syncthreads();

    const int wdx = ((blk << 1) + win) & 63;
    const f32x4* bw4 = (const f32x4*)(bmF + ((((size_t)(wdx * HEADS + h)) * 4 + wq) * 4 * 64 + l) * 4);
    f32x4 bmv[4];
    #pragma unroll
    for (int kt = 0; kt < 4; ++kt) bmv[kt] = bw4[kt * 64];

    f32x4 sacc[4] = {};
    {
      bf16x8 aq = *(const bf16x8*)&qsw[(wq * 16 + c) * 40 + g * 8];
      #pragma unroll
      for (int kt = 0; kt < 4; ++kt) {
        bf16x8 bk = *(const bf16x8*)&ksw[(kt * 16 + c) * 40 + g * 8];
        sacc[kt] = __builtin_amdgcn_mfma_f32_16x16x32_bf16(aq, bk, sacc[kt], 0, 0, 0);
      }
    }
    float p[4][4];
    #pragma unroll
    for (int r = 0; r < 4; ++r) {
      float s0 = sacc[0][r] + bmv[0][r], s1 = sacc[1][r] + bmv[1][r];
      float s2 = sacc[2][r] + bmv[2][r], s3 = sacc[3][r] + bmv[3][r];
      float mx = fmaxf(fmaxf(s0, s1), fmaxf(s2, s3));
      mx = fmaxf(mx, __shfl_xor(mx, 1, 64));
      mx = fmaxf(mx, __shfl_xor(mx, 2, 64));
      mx = fmaxf(mx, __shfl_xor(mx, 4, 64));
      mx = fmaxf(mx, __shfl_xor(mx, 8, 64));
      float p0 = __builtin_exp2f((s0 - mx) * LOG2E);
      float p1 = __builtin_exp2f((s1 - mx) * LOG2E);
      float p2 = __builtin_exp2f((s2 - mx) * LOG2E);
      float p3 = __builtin_exp2f((s3 - mx) * LOG2E);
      float sum = p0 + p1 + p2 + p3;
      sum += __shfl_xor(sum, 1, 64);
      sum += __shfl_xor(sum, 2, 64);
      sum += __shfl_xor(sum, 4, 64);
      sum += __shfl_xor(sum, 8, 64);
      float inv = 1.0f / sum;
      p[0][r] = p0 * inv; p[1][r] = p1 * inv; p[2][r] = p2 * inv; p[3][r] = p3 * inv;
    }
    f32x4 pacc2[2] = {};
    #pragma unroll
    for (int kkh = 0; kkh < 2; ++kkh) {
      #pragma unroll
      for (int t = 0; t < 2; ++t) {
        int kt = kkh * 2 + t;
        #pragma unroll
        for (int r = 0; r < 4; ++r)
          psw[(wq * 16 + g * 4 + r) * 40 + t * 16 + c] = f2bf(p[kt][r]);
      }
      bf16x8 ap = *(const bf16x8*)&psw[(wq * 16 + c) * 40 + g * 8];
      #pragma unroll
      for (int dt = 0; dt < 2; ++dt) {
        bf16x8 bv = *(const bf16x8*)&vtw[(dt * 16 + c) * 72 + kkh * 32 + g * 8];
        pacc2[dt] = __builtin_amdgcn_mfma_f32_16x16x32_bf16(ap, bv, pacc2[dt], 0, 0, 0);
      }
    }
    #pragma unroll
    for (int dt = 0; dt < 2; ++dt) {
      int gr0 = h * 4 + dt * 2 + (c >> 3);
      #pragma unroll
      for (int rr = 0; rr < 4; ++rr) {
        int tok = wq * 16 + g * 4 + rr;
        int row0 = win * 49 + tok;
        if (tok < NWIN)
          ao[row0 * 384 + (((gr0 ^ (row0 & 7)) << 3) | (c & 7))] = f2bf(pacc2[dt][rr]);
      }
    }
    __syncthreads();
  }

  __syncthreads();
  for (int nb = 0; nb < 4; ++nb) {
    f32x4 acc[2][3] = {};
    const int pb0 = (nb * 3) & 1;
    compute_proj(0, pb0, acc);
    __syncthreads();
    stage_proj(nb, 2, pb0);
    compute_proj(1, pb0 ^ 1, acc);
    __syncthreads();
    if (nb < 3) stage_proj(nb + 1, 0, pb0 ^ 1);
    compute_proj(2, pb0, acc);
    __syncthreads();
    if (nb < 3) stage_proj(nb + 1, 1, pb0);
    #pragma unroll
    for (int nt = 0; nt < 3; ++nt) {
      int col = nb * 96 + (wn * 3 + nt) * 16 + c;
      float pb = proj_b[col];
      #pragma unroll
      for (int mt = 0; mt < 2; ++mt) {
        #pragma unroll
        for (int r = 0; r < 4; ++r) {
          int mrow = wm * 32 + mt * 16 + g * 4 + r;
          if (mrow < 98) {
            int wi = mrow >= NWIN;
            int tok = mrow - (wi ? NWIN : 0);
            out[((size_t)((blk << 1) + wi) * NWIN + tok) * DIM + col] = acc[mt][nt][r] + pb;
          }
        }
      }
    }
  }
}

extern "C" void kernel_launch(void* const* d_in, const int* in_sizes, int n_in,
                              void* d_out, int out_size, void* d_ws, size_t ws_size,
                              hipStream_t stream) {
  const float* x          = (const float*)d_in[0];
  const float* mask       = (const float*)d_in[1];
  const float* bias_table = (const float*)d_in[2];
  const float* qkv_w      = (const float*)d_in[3];
  const float* qkv_b      = (const float*)d_in[4];
  const float* proj_w     = (const float*)d_in[5];
  const float* proj_b     = (const float*)d_in[6];
  const int*   rel_index  = (const int*)d_in[7];
  float* out = (float*)d_out;

  // ws: wqb @0 | wpb @884736 | qbF @1179648 | bmF @1184256 |
  //     qg @13767168 | kg @167907840 | vg @322048512 | end 476189184
  ushort* wqb = (ushort*)d_ws;
  ushort* wpb = (ushort*)((char*)d_ws + 884736);
  float*  qbF = (float*)((char*)d_ws + 1179648);
  float*  bmF = (float*)((char*)d_ws + 1184256);
  ushort* qg  = (ushort*)((char*)d_ws + 13767168);
  ushort* kg  = (ushort*)((char*)d_ws + 167907840);
  ushort* vg  = (ushort*)((char*)d_ws + 322048512);
  const size_t NEED = 476189184ull;

  prep_kernel<<<1024, 256, 0, stream>>>(qkv_w, proj_w, bias_table, rel_index, mask, qkv_b,
                                        wqb, wpb, qbF, bmF);

  if (ws_size >= NEED) {
    hipFuncSetAttribute((const void*)qkv_gemm_kernel,
                        hipFuncAttributeMaxDynamicSharedMemorySize, 65536);
    qkv_gemm_kernel<<<14112, 256, 65536, stream>>>(x, qbF, wqb, qg, kg, vg);
    attn_kernel<<<12288, 256, 0, stream>>>(kg, vg, bmF, qg);
    hipFuncSetAttribute((const void*)proj_kernel,
                        hipFuncAttributeMaxDynamicSharedMemorySize, 65536);
    proj_kernel<<<4704, 256, 65536, stream>>>(qg, wpb, proj_b, out);
  } else {
    hipFuncSetAttribute((const void*)winattn_fused,
                        hipFuncAttributeMaxDynamicSharedMemorySize, FSMEM_US * 2);
    winattn_fused<<<2048, 512, FSMEM_US * 2, stream>>>(x, qbF, proj_b, wqb, wpb, bmF, out);
  }
}

// Round 12
// 794.632 us; speedup vs baseline: 1.1799x; 1.1699x over previous
//
#include <hip/hip_runtime.h>
#include <hip/hip_bf16.h>

#define DIM   384
#define NWIN  49
#define HEADS 12
#define SCALE 0.17677669529663687f

typedef unsigned short ushort;
using bf16x8 = __attribute__((ext_vector_type(8))) short;
using u16x4  = __attribute__((ext_vector_type(4))) ushort;
using f32x4  = __attribute__((ext_vector_type(4))) float;

__device__ __forceinline__ ushort f2bf(float f) {
  unsigned u = __float_as_uint(f);
  u += 0x7fff + ((u >> 16) & 1);          // RNE
  return (ushort)(u >> 16);
}

typedef __attribute__((address_space(1))) const void gas_void;
typedef __attribute__((address_space(3))) void las_void;

__device__ __forceinline__ void gload16(const ushort* g, ushort* l) {
  __builtin_amdgcn_global_load_lds((gas_void*)g, (las_void*)l, 16, 0, 0);
}

// ===================== prep (verbatim r10/r8) =====================
__global__ void prep_kernel(const float* __restrict__ qkv_w, const float* __restrict__ proj_w,
                            const float* __restrict__ bias_table, const int* __restrict__ rel_index,
                            const float* __restrict__ mask, const float* __restrict__ qkv_b,
                            ushort* __restrict__ wqb, ushort* __restrict__ wpb,
                            float* __restrict__ qbF, float* __restrict__ bmF) {
  int i0 = blockIdx.x * 256 + threadIdx.x;
  int stride = gridDim.x * 256;
  for (int i = i0; i < 1152 * 384; i += stride) {
    float v = qkv_w[i];
    if (i < 384 * 384) v *= SCALE;                 // fold softmax scale into Wq
    wqb[i] = f2bf(v);
  }
  for (int i = i0; i < 384 * 384; i += stride) wpb[i] = f2bf(proj_w[i]);
  for (int i = i0; i < 1152; i += stride) qbF[i] = qkv_b[i] * (i < 384 ? SCALE : 1.f);
  for (int i = i0; i < 64 * HEADS * 4 * 4 * 64 * 4; i += stride) {
    int r = i & 3, lane = (i >> 2) & 63, kt = (i >> 8) & 3, wq = (i >> 10) & 3;
    int hw = i >> 12;
    int h = hw % HEADS, wdx = hw / HEADS;
    int q = wq * 16 + (lane >> 4) * 4 + r;
    int key = kt * 16 + (lane & 15);
    float v;
    if (q < NWIN)
      v = (key < NWIN) ? bias_table[rel_index[q * NWIN + key] * HEADS + h]
                         + mask[wdx * (NWIN * NWIN) + q * NWIN + key]
                       : -3.0e38f;
    else
      v = 0.f;
    bmF[i] = v;
  }
}

// ===================== x -> bf16 (dedicated, exact grid: 75264 x 256) =====================
__global__ __launch_bounds__(256) void x2bf_kernel(const float* __restrict__ x,
                                                   ushort* __restrict__ xbf) {
  size_t i = (size_t)blockIdx.x * 256 + threadIdx.x;   // < 19267584 float4s exactly
  float4 f = ((const float4*)x)[i];
  u16x4 v4 = { f2bf(f.x), f2bf(f.y), f2bf(f.z), f2bf(f.w) };
  ((u16x4*)xbf)[i] = v4;
}

// ============ kernel A (tier-1): QKV mega-GEMM, A from bf16 xbf ============
// XCD-panel-affinity: 14112 blocks = 8 xcd x 196 panels x 9 N-blocks; the 9 blocks
// sharing an A panel land consecutively on one XCD -> panel re-reads hit that L2.
__global__ __launch_bounds__(256) void qkv_gemm_bf16_kernel(
    const ushort* __restrict__ xbf, const float* __restrict__ qbF,
    const ushort* __restrict__ wqb,
    ushort* __restrict__ qg, ushort* __restrict__ kg, ushort* __restrict__ vg)
{
  extern __shared__ ushort smA[];
  ushort* lA = smA;                  // 2 x [128][64]
  ushort* lB = smA + 16384;          // 2 x [128][64]

  const int hw = blockIdx.x;
  const int xcd = hw & 7, slot = hw >> 3;
  const int pan = slot / 9, bN = slot - pan * 9;
  const int bM = (pan << 3) + xcd;
  const int m0 = bM * 128, n0 = bN * 128;
  const int which = bN / 3;                    // 0=q 1=k 2=v
  ushort* outw = which == 0 ? qg : (which == 1 ? kg : vg);
  const int tid = threadIdx.x;
  const int w = tid >> 6, l = tid & 63;
  const int c = l & 15, g = l >> 4;
  const int wm = w >> 1, wn = w & 1;           // wave tile 64 x 64

  // stageA: bf16x8 reg load + ds_write to the SAME swizzled position as the
  // verified fp32 path (only the source load changed fp32->bf16).
  auto stageA = [&](int kc, int buf) {
    #pragma unroll
    for (int s = 0; s < 4; ++s) {
      int i = s * 256 + tid;
      int row = i >> 3, gc = i & 7;
      bf16x8 vx = *(const bf16x8*)(xbf + (size_t)(m0 + row) * DIM + kc * 64 + gc * 8);
      *(bf16x8*)&lA[buf * 8192 + row * 64 + ((gc ^ (row & 7)) << 3)] = vx;
    }
  };
  auto stageB = [&](int kc, int buf) {
    #pragma unroll
    for (int s = 0; s < 4; ++s) {
      int i = s * 256 + tid;
      int row = i >> 3, gc = i & 7;
      gload16(wqb + (size_t)(n0 + row) * DIM + kc * 64 + ((gc ^ (row & 7)) << 3),
              lB + buf * 8192 + i * 8);
    }
  };

  f32x4 acc[4][4] = {};
  stageA(0, 0); stageB(0, 0);
  stageA(1, 1); stageB(1, 1);
  __syncthreads();

  for (int kc = 0; kc < 6; ++kc) {
    const ushort* A = lA + (kc & 1) * 8192;
    const ushort* B = lB + (kc & 1) * 8192;
    #pragma unroll
    for (int kk = 0; kk < 2; ++kk) {
      int swz = ((kk * 4 + g) ^ (c & 7)) << 3;
      bf16x8 af[4], bfr[4];
      #pragma unroll
      for (int mt = 0; mt < 4; ++mt)
        af[mt] = *(const bf16x8*)&A[(wm * 64 + mt * 16 + c) * 64 + swz];
      #pragma unroll
      for (int nt = 0; nt < 4; ++nt)
        bfr[nt] = *(const bf16x8*)&B[(wn * 64 + nt * 16 + c) * 64 + swz];
      #pragma unroll
      for (int mt = 0; mt < 4; ++mt)
        #pragma unroll
        for (int nt = 0; nt < 4; ++nt)
          acc[mt][nt] = __builtin_amdgcn_mfma_f32_16x16x32_bf16(af[mt], bfr[nt], acc[mt][nt], 0, 0, 0);
    }
    __syncthreads();
    if (kc + 2 < 6) { stageA(kc + 2, kc & 1); stageB(kc + 2, kc & 1); }
  }

  #pragma unroll
  for (int nt = 0; nt < 4; ++nt) {
    int n = n0 + wn * 64 + nt * 16 + c;
    int h = (n - which * 384) >> 5;
    int d = n & 31;
    float qb_ = qbF[n];
    #pragma unroll
    for (int mt = 0; mt < 4; ++mt) {
      #pragma unroll
      for (int r = 0; r < 4; ++r) {
        int tok = m0 + wm * 64 + mt * 16 + g * 4 + r;
        int win = tok / 49;
        int tk = tok - win * 49;
        outw[((size_t)(win * HEADS + h) * NWIN + tk) * 32 + d] = f2bf(acc[mt][nt][r] + qb_);
      }
    }
  }
}

// ============ kernel A (tier-2): QKV mega-GEMM, A from fp32 x (r10-exact + swizzle) ====
__global__ __launch_bounds__(256) void qkv_gemm_kernel(
    const float* __restrict__ x, const float* __restrict__ qbF,
    const ushort* __restrict__ wqb,
    ushort* __restrict__ qg, ushort* __restrict__ kg, ushort* __restrict__ vg)
{
  extern __shared__ ushort smA[];
  ushort* lA = smA;                  // 2 x [128][64]
  ushort* lB = smA + 16384;          // 2 x [128][64]

  const int hw = blockIdx.x;
  const int xcd = hw & 7, slot = hw >> 3;
  const int pan = slot / 9, bN = slot - pan * 9;
  const int bM = (pan << 3) + xcd;
  const int m0 = bM * 128, n0 = bN * 128;
  const int which = bN / 3;                    // 0=q 1=k 2=v
  ushort* outw = which == 0 ? qg : (which == 1 ? kg : vg);
  const int tid = threadIdx.x;
  const int w = tid >> 6, l = tid & 63;
  const int c = l & 15, g = l >> 4;
  const int wm = w >> 1, wn = w & 1;           // wave tile 64 x 64

  auto stageA = [&](int kc, int buf) {         // fp32 x -> bf16, swizzled LDS write
    #pragma unroll
    for (int s = 0; s < 4; ++s) {
      int i = s * 256 + tid;
      int row = i >> 3, gc = i & 7;
      const float4* src = (const float4*)(x + (size_t)(m0 + row) * DIM + kc * 64 + gc * 8);
      float4 f0 = src[0], f1 = src[1];
      ushort tmp[8] = { f2bf(f0.x), f2bf(f0.y), f2bf(f0.z), f2bf(f0.w),
                        f2bf(f1.x), f2bf(f1.y), f2bf(f1.z), f2bf(f1.w) };
      *(bf16x8*)&lA[buf * 8192 + row * 64 + ((gc ^ (row & 7)) << 3)] = *(bf16x8*)tmp;
    }
  };
  auto stageB = [&](int kc, int buf) {
    #pragma unroll
    for (int s = 0; s < 4; ++s) {
      int i = s * 256 + tid;
      int row = i >> 3, gc = i & 7;
      gload16(wqb + (size_t)(n0 + row) * DIM + kc * 64 + ((gc ^ (row & 7)) << 3),
              lB + buf * 8192 + i * 8);
    }
  };

  f32x4 acc[4][4] = {};
  stageA(0, 0); stageB(0, 0);
  stageA(1, 1); stageB(1, 1);
  __syncthreads();

  for (int kc = 0; kc < 6; ++kc) {
    const ushort* A = lA + (kc & 1) * 8192;
    const ushort* B = lB + (kc & 1) * 8192;
    #pragma unroll
    for (int kk = 0; kk < 2; ++kk) {
      int swz = ((kk * 4 + g) ^ (c & 7)) << 3;
      bf16x8 af[4], bfr[4];
      #pragma unroll
      for (int mt = 0; mt < 4; ++mt)
        af[mt] = *(const bf16x8*)&A[(wm * 64 + mt * 16 + c) * 64 + swz];
      #pragma unroll
      for (int nt = 0; nt < 4; ++nt)
        bfr[nt] = *(const bf16x8*)&B[(wn * 64 + nt * 16 + c) * 64 + swz];
      #pragma unroll
      for (int mt = 0; mt < 4; ++mt)
        #pragma unroll
        for (int nt = 0; nt < 4; ++nt)
          acc[mt][nt] = __builtin_amdgcn_mfma_f32_16x16x32_bf16(af[mt], bfr[nt], acc[mt][nt], 0, 0, 0);
    }
    __syncthreads();
    if (kc + 2 < 6) { stageA(kc + 2, kc & 1); stageB(kc + 2, kc & 1); }
  }

  #pragma unroll
  for (int nt = 0; nt < 4; ++nt) {
    int n = n0 + wn * 64 + nt * 16 + c;
    int h = (n - which * 384) >> 5;
    int d = n & 31;
    float qb_ = qbF[n];
    #pragma unroll
    for (int mt = 0; mt < 4; ++mt) {
      #pragma unroll
      for (int r = 0; r < 4; ++r) {
        int tok = m0 + wm * 64 + mt * 16 + g * 4 + r;
        int win = tok / 49;
        int tk = tok - win * 49;
        outw[((size_t)(win * HEADS + h) * NWIN + tk) * 32 + d] = f2bf(acc[mt][nt][r] + qb_);
      }
    }
  }
}

// ============ kernel B: barrier-free attention (r10-exact, scalar v staging) ============
#define VSTR 68
__global__ __launch_bounds__(256) void attn_kernel(
    const ushort* __restrict__ kg, const ushort* __restrict__ vg,
    const float* __restrict__ bmF, ushort* __restrict__ qg)
{
  __shared__ ushort vts[4][32 * VSTR];
  __shared__ ushort pbs[4][16 * 36];

  const int tid = threadIdx.x;
  const int w = tid >> 6, l = tid & 63;
  const int c = l & 15, g = l >> 4;
  const int task = blockIdx.x * 4 + w;
  const int win = task / 12, h = task - win * 12;
  const int wdx = win & 63;
  const float LOG2E = 1.4426950408889634f;

  const size_t sb = (size_t)(win * HEADS + h) * (NWIN * 32);
  ushort* qslice = qg + sb;                    // read q, then overwrite with attn-out
  const ushort* kb = kg + sb;
  const ushort* vb = vg + sb;
  ushort* vt = vts[w];
  ushort* pb = pbs[w];

  // q,k fragments: coalesced global -> regs (rows >=49 read garbage; masked later)
  bf16x8 qf[4], kf[4];
  #pragma unroll
  for (int t = 0; t < 4; ++t) {
    qf[t] = *(const bf16x8*)(qslice + (t * 16 + c) * 32 + g * 8);
    kf[t] = *(const bf16x8*)(kb + (t * 16 + c) * 32 + g * 8);
  }
  // v -> vT LDS (wave-private; within-wave lgkmcnt ordering, no barrier)
  #pragma unroll
  for (int it = 0; it < 25; ++it) {
    int i = it * 64 + l;
    if (i < NWIN * 32) vt[(i & 31) * VSTR + (i >> 5)] = vb[i];
  }
  for (int i = l; i < 32 * 15; i += 64) {      // zero keys 49..63
    int d = i / 15, t = NWIN + (i - d * 15);
    vt[d * VSTR + t] = 0;
  }

  const float* bmBase = bmF + (size_t)((wdx * HEADS + h) * 4) * 1024 + l * 4;

  #pragma unroll
  for (int qt = 0; qt < 4; ++qt) {
    f32x4 sacc[4] = {};
    #pragma unroll
    for (int kt = 0; kt < 4; ++kt)
      sacc[kt] = __builtin_amdgcn_mfma_f32_16x16x32_bf16(qf[qt], kf[kt], sacc[kt], 0, 0, 0);
    const f32x4* bw4 = (const f32x4*)(bmBase + qt * 1024);
    float p[4][4];
    {
      f32x4 b0 = bw4[0], b1 = bw4[64], b2 = bw4[128], b3 = bw4[192];
      #pragma unroll
      for (int r = 0; r < 4; ++r) {
        float s0 = sacc[0][r] + b0[r], s1 = sacc[1][r] + b1[r];
        float s2 = sacc[2][r] + b2[r], s3 = sacc[3][r] + b3[r];
        float mx = fmaxf(fmaxf(s0, s1), fmaxf(s2, s3));
        mx = fmaxf(mx, __shfl_xor(mx, 1, 64));
        mx = fmaxf(mx, __shfl_xor(mx, 2, 64));
        mx = fmaxf(mx, __shfl_xor(mx, 4, 64));
        mx = fmaxf(mx, __shfl_xor(mx, 8, 64));
        float p0 = __builtin_exp2f((s0 - mx) * LOG2E);
        float p1 = __builtin_exp2f((s1 - mx) * LOG2E);
        float p2 = __builtin_exp2f((s2 - mx) * LOG2E);
        float p3 = __builtin_exp2f((s3 - mx) * LOG2E);
        float sum = p0 + p1 + p2 + p3;
        sum += __shfl_xor(sum, 1, 64);
        sum += __shfl_xor(sum, 2, 64);
        sum += __shfl_xor(sum, 4, 64);
        sum += __shfl_xor(sum, 8, 64);
        float inv = 1.0f / sum;
        p[0][r] = p0 * inv; p[1][r] = p1 * inv; p[2][r] = p2 * inv; p[3][r] = p3 * inv;
      }
    }
    // PV in two 32-key halves through wave-private P buffer
    f32x4 pacc[2] = {};
    #pragma unroll
    for (int kkh = 0; kkh < 2; ++kkh) {
      #pragma unroll
      for (int t = 0; t < 2; ++t) {
        int kt = kkh * 2 + t;
        #pragma unroll
        for (int r = 0; r < 4; ++r)
          pb[(g * 4 + r) * 36 + t * 16 + c] = f2bf(p[kt][r]);
      }
      bf16x8 ap = *(const bf16x8*)&pb[c * 36 + g * 8];
      #pragma unroll
      for (int dt = 0; dt < 2; ++dt) {
        bf16x8 bv = *(const bf16x8*)&vt[(dt * 16 + c) * VSTR + kkh * 32 + g * 8];
        pacc[dt] = __builtin_amdgcn_mfma_f32_16x16x32_bf16(ap, bv, pacc[dt], 0, 0, 0);
      }
    }
    // attn-out overwrites own q slice (q already in regs)
    #pragma unroll
    for (int dt = 0; dt < 2; ++dt) {
      #pragma unroll
      for (int rr = 0; rr < 4; ++rr) {
        int tok = qt * 16 + g * 4 + rr;
        if (tok < NWIN)
          qslice[tok * 32 + dt * 16 + c] = f2bf(pacc[dt][rr]);
      }
    }
  }
}

// ============ kernel C: proj GEMM 128x128 K=384 (r10-exact + XCD swizzle) =======
__global__ __launch_bounds__(256, 2) void proj_kernel(
    const ushort* __restrict__ ao, const ushort* __restrict__ wpb,
    const float* __restrict__ proj_b, float* __restrict__ out)
{
  extern __shared__ ushort sm3[];
  ushort* lA = sm3;                  // 2 x [128][64]
  ushort* lB = sm3 + 16384;          // 2 x [128][64]

  const int hw = blockIdx.x;         // 4704 = 8 xcd x 196 panels x 3 N-blocks
  const int xcd = hw & 7, slot = hw >> 3;
  const int pan = slot / 3, bN = slot - pan * 3;
  const int bM = (pan << 3) + xcd;
  const int m0 = bM * 128, n0 = bN * 128;
  const int tid = threadIdx.x;
  const int w = tid >> 6, l = tid & 63;
  const int c = l & 15, g = l >> 4;
  const int wm = w >> 1, wn = w & 1;   // wave tile 64 x 64

  auto stageA = [&](int kc, int buf) {
    #pragma unroll
    for (int s = 0; s < 4; ++s) {
      int i = s * 256 + tid;
      int row = i >> 3, gc = i & 7;
      int tok = m0 + row;
      int win = tok / 49;
      int tk = tok - win * 49;
      int sg = gc ^ (row & 7);
      int kfull = kc * 64 + sg * 8;
      gload16(ao + ((size_t)(win * HEADS + (kfull >> 5)) * NWIN + tk) * 32 + (kfull & 31),
              lA + buf * 8192 + i * 8);
    }
  };
  auto stageB = [&](int kc, int buf) {
    #pragma unroll
    for (int s = 0; s < 4; ++s) {
      int i = s * 256 + tid;
      int row = i >> 3, gc = i & 7;
      gload16(wpb + (size_t)(n0 + row) * DIM + kc * 64 + ((gc ^ (row & 7)) << 3),
              lB + buf * 8192 + i * 8);
    }
  };

  f32x4 acc[4][4] = {};
  stageA(0, 0); stageB(0, 0);
  stageA(1, 1); stageB(1, 1);
  __syncthreads();

  for (int kc = 0; kc < 6; ++kc) {
    const ushort* A = lA + (kc & 1) * 8192;
    const ushort* B = lB + (kc & 1) * 8192;
    #pragma unroll
    for (int kk = 0; kk < 2; ++kk) {
      int swz = ((kk * 4 + g) ^ (c & 7)) << 3;
      bf16x8 af[4], bfr[4];
      #pragma unroll
      for (int mt = 0; mt < 4; ++mt)
        af[mt] = *(const bf16x8*)&A[(wm * 64 + mt * 16 + c) * 64 + swz];
      #pragma unroll
      for (int nt = 0; nt < 4; ++nt)
        bfr[nt] = *(const bf16x8*)&B[(wn * 64 + nt * 16 + c) * 64 + swz];
      #pragma unroll
      for (int mt = 0; mt < 4; ++mt)
        #pragma unroll
        for (int nt = 0; nt < 4; ++nt)
          acc[mt][nt] = __builtin_amdgcn_mfma_f32_16x16x32_bf16(af[mt], bfr[nt], acc[mt][nt], 0, 0, 0);
    }
    __syncthreads();
    if (kc + 2 < 6) { stageA(kc + 2, kc & 1); stageB(kc + 2, kc & 1); }
  }

  #pragma unroll
  for (int nt = 0; nt < 4; ++nt) {
    int col = n0 + wn * 64 + nt * 16 + c;
    float pb = proj_b[col];
    #pragma unroll
    for (int mt = 0; mt < 4; ++mt) {
      #pragma unroll
      for (int r = 0; r < 4; ++r) {
        int row = m0 + wm * 64 + mt * 16 + g * 4 + r;
        out[(size_t)row * DIM + col] = acc[mt][nt][r] + pb;
      }
    }
  }
}

// ===================== fallback: EXACT r8 monolith (verbatim) =====================
#define FWB_OFF 0
#define FQS_OFF 24576
#define FKS_OFF 29696
#define FVT_OFF 34816
#define FAO_OFF 39424
#define FSMEM_US 77056   // 154112 bytes

__global__ __launch_bounds__(512, 2) void winattn_fused(
    const float* __restrict__ x, const float* __restrict__ qbF,
    const float* __restrict__ proj_b, const ushort* __restrict__ wqb,
    const ushort* __restrict__ wpb, const float* __restrict__ bmF,
    float* __restrict__ out)
{
  extern __shared__ ushort smem[];
  ushort* wb = smem + FWB_OFF;
  ushort* ao = smem + FAO_OFF;

  const int blk = blockIdx.x;
  const int tid = threadIdx.x;
  const int w = tid >> 6, l = tid & 63;
  const int c = l & 15, g = l >> 4;
  const int wm = w >> 1, wn = w & 1;
  const int win = w >> 2, wq = w & 3;
  const float LOG2E = 1.4426950408889634f;

  ushort* qsw = smem + FQS_OFF + win * 2560;
  ushort* ksw = smem + FKS_OFF + win * 2560;
  ushort* vtw = smem + FVT_OFF + win * 2304;
  ushort* psw = qsw;

  auto stage_qkv = [&](int h, int kc, int buf) {
    #pragma unroll
    for (int s = 0; s < 3; ++s) {
      int i = s * 512 + tid;
      int n = i >> 4, g16 = i & 15;
      int grow = (n >> 5) * 384 + h * 32 + (n & 31);
      int sg = (g16 & 8) | ((g16 & 7) ^ (n & 7));
      gload16(wqb + (size_t)grow * DIM + kc * 128 + (sg << 3), wb + buf * 12288 + i * 8);
    }
  };
  auto stage_proj = [&](int nb, int kc, int buf) {
    #pragma unroll
    for (int s = 0; s < 3; ++s) {
      int i = s * 512 + tid;
      int n = i >> 4, g16 = i & 15;
      int grow = nb * 96 + n;
      int sg = (g16 & 8) | ((g16 & 7) ^ (n & 7));
      gload16(wpb + (size_t)grow * DIM + kc * 128 + (sg << 3), wb + buf * 12288 + i * 8);
    }
  };

  bf16x8 areg[2][12] = {};
  auto compute_qkv = [&](int kcC, int buf, f32x4 (&acc)[2][3]) {
    const ushort* wcb = wb + buf * 12288;
    #pragma unroll
    for (int kk = 0; kk < 4; ++kk) {
      int sB = ((kk * 4 + g) ^ (c & 7)) << 3;
      #pragma unroll
      for (int nt = 0; nt < 3; ++nt) {
        int n = (wn * 3 + nt) * 16 + c;
        bf16x8 bb = *(const bf16x8*)&wcb[n * 128 + sB];
        acc[0][nt] = __builtin_amdgcn_mfma_f32_16x16x32_bf16(areg[0][kcC * 4 + kk], bb, acc[0][nt], 0, 0, 0);
        acc[1][nt] = __builtin_amdgcn_mfma_f32_16x16x32_bf16(areg[1][kcC * 4 + kk], bb, acc[1][nt], 0, 0, 0);
      }
    }
  };
  auto compute_proj = [&](int kcC, int buf, f32x4 (&acc)[2][3]) {
    const ushort* wcb = wb + buf * 12288;
    int r0 = wm * 32 + c;      if (r0 >= 98) r0 -= 64;
    int r1 = wm * 32 + 16 + c; if (r1 >= 98) r1 -= 64;
    #pragma unroll
    for (int kk = 0; kk < 4; ++kk) {
      int p = kcC * 16 + kk * 4 + g;
      int sw = (p ^ (c & 7)) << 3;
      bf16x8 a0 = *(const bf16x8*)&ao[r0 * 384 + sw];
      bf16x8 a1 = *(const bf16x8*)&ao[r1 * 384 + sw];
      int sB = ((kk * 4 + g) ^ (c & 7)) << 3;
      #pragma unroll
      for (int nt = 0; nt < 3; ++nt) {
        int n = (wn * 3 + nt) * 16 + c;
        bf16x8 bb = *(const bf16x8*)&wcb[n * 128 + sB];
        acc[0][nt] = __builtin_amdgcn_mfma_f32_16x16x32_bf16(a0, bb, acc[0][nt], 0, 0, 0);
        acc[1][nt] = __builtin_amdgcn_mfma_f32_16x16x32_bf16(a1, bb, acc[1][nt], 0, 0, 0);
      }
    }
  };

  stage_qkv(0, 0, 0);
  stage_qkv(0, 1, 1);
  {
    const float* xb = x + (size_t)blk * (2 * NWIN * DIM);
    for (int i = tid; i < 9408; i += 512) {
      float4 f = ((const float4*)xb)[i];
      int row = i / 96, c4 = i - row * 96;
      int k = c4 * 4;
      int gr = k >> 3;
      u16x4 v4 = { f2bf(f.x), f2bf(f.y), f2bf(f.z), f2bf(f.w) };
      *(u16x4*)&ao[row * 384 + ((gr ^ (row & 7)) << 3) + (k & 7)] = v4;
    }
  }
  __syncthreads();
  #pragma unroll
  for (int mt = 0; mt < 2; ++mt) {
    int row = wm * 32 + mt * 16 + c;
    int wi = row >> 6, tok = row & 63;
    if (tok < NWIN) {
      int ar = wi * 49 + tok;
      #pragma unroll
      for (int kg = 0; kg < 12; ++kg)
        areg[mt][kg] = *(const bf16x8*)&ao[ar * 384 + (((kg * 4 + g) ^ (ar & 7)) << 3)];
    }
  }

  for (int h = 0; h < HEADS; ++h) {
    f32x4 acc[2][3] = {};
    const int par = h & 1;
    compute_qkv(0, par, acc);
    __syncthreads();
    stage_qkv(h, 2, par);
    compute_qkv(1, par ^ 1, acc);
    __syncthreads();
    if (h < 11) stage_qkv(h + 1, 0, par ^ 1); else stage_proj(0, 0, par ^ 1);
    compute_qkv(2, par, acc);
    __syncthreads();
    if (h < 11) stage_qkv(h + 1, 1, par); else stage_proj(0, 1, par);
    {
      int winE = wm >> 1;
      ushort* qsE = smem + FQS_OFF + winE * 2560;
      ushort* ksE = smem + FKS_OFF + winE * 2560;
      ushort* vtE = smem + FVT_OFF + winE * 2304;
      #pragma unroll
      for (int nt = 0; nt < 3; ++nt) {
        int gnt = wn * 3 + nt;
        int which = gnt >> 1;
        int d = (gnt & 1) * 16 + c;
        float qb_ = qbF[which * 384 + h * 32 + d];
        #pragma unroll
        for (int mt = 0; mt < 2; ++mt) {
          #pragma unroll
          for (int r = 0; r < 4; ++r) {
            int tok = (wm & 1) * 32 + mt * 16 + g * 4 + r;
            float v = acc[mt][nt][r] + qb_;
            if (which == 0)      qsE[tok * 40 + d] = f2bf(v);
            else if (which == 1) ksE[tok * 40 + d] = f2bf(v);
            else                 vtE[d * 72 + tok] = f2bf(v);
          }
        }
      }
    }
    __syncthreads();

    const int wdx = ((blk << 1) + win) & 63;
    const f32x4* bw4 = (const f32x4*)(bmF + ((((size_t)(wdx * HEADS + h)) * 4 + wq) * 4 * 64 + l) * 4);
    f32x4 bmv[4];
    #pragma unroll
    for (int kt = 0; kt < 4; ++kt) bmv[kt] = bw4[kt * 64];

    f32x4 sacc[4] = {};
    {
      bf16x8 aq = *(const bf16x8*)&qsw[(wq * 16 + c) * 40 + g * 8];
      #pragma unroll
      for (int kt = 0; kt < 4; ++kt) {
        bf16x8 bk = *(const bf16x8*)&ksw[(kt * 16 + c) * 40 + g * 8];
        sacc[kt] = __builtin_amdgcn_mfma_f32_16x16x32_bf16(aq, bk, sacc[kt], 0, 0, 0);
      }
    }
    float p[4][4];
    #pragma unroll
    for (int r = 0; r < 4; ++r) {
      float s0 = sacc[0][r] + bmv[0][r], s1 = sacc[1][r] + bmv[1][r];
      float s2 = sacc[2][r] + bmv[2][r], s3 = sacc[3][r] + bmv[3][r];
      float mx = fmaxf(fmaxf(s0, s1), fmaxf(s2, s3));
      mx = fmaxf(mx, __shfl_xor(mx, 1, 64));
      mx = fmaxf(mx, __shfl_xor(mx, 2, 64));
      mx = fmaxf(mx, __shfl_xor(mx, 4, 64));
      mx = fmaxf(mx, __shfl_xor(mx, 8, 64));
      float p0 = __builtin_exp2f((s0 - mx) * LOG2E);
      float p1 = __builtin_exp2f((s1 - mx) * LOG2E);
      float p2 = __builtin_exp2f((s2 - mx) * LOG2E);
      float p3 = __builtin_exp2f((s3 - mx) * LOG2E);
      float sum = p0 + p1 + p2 + p3;
      sum += __shfl_xor(sum, 1, 64);
      sum += __shfl_xor(sum, 2, 64);
      sum += __shfl_xor(sum, 4, 64);
      sum += __shfl_xor(sum, 8, 64);
      float inv = 1.0f / sum;
      p[0][r] = p0 * inv; p[1][r] = p1 * inv; p[2][r] = p2 * inv; p[3][r] = p3 * inv;
    }
    f32x4 pacc2[2] = {};
    #pragma unroll
    for (int kkh = 0; kkh < 2; ++kkh) {
      #pragma unroll
      for (int t = 0; t < 2; ++t) {
        int kt = kkh * 2 + t;
        #pragma unroll
        for (int r = 0; r < 4; ++r)
          psw[(wq * 16 + g * 4 + r) * 40 + t * 16 + c] = f2bf(p[kt][r]);
      }
      bf16x8 ap = *(const bf16x8*)&psw[(wq * 16 + c) * 40 + g * 8];
      #pragma unroll
      for (int dt = 0; dt < 2; ++dt) {
        bf16x8 bv = *(const bf16x8*)&vtw[(dt * 16 + c) * 72 + kkh * 32 + g * 8];
        pacc2[dt] = __builtin_amdgcn_mfma_f32_16x16x32_bf16(ap, bv, pacc2[dt], 0, 0, 0);
      }
    }
    #pragma unroll
    for (int dt = 0; dt < 2; ++dt) {
      int gr0 = h * 4 + dt * 2 + (c >> 3);
      #pragma unroll
      for (int rr = 0; rr < 4; ++rr) {
        int tok = wq * 16 + g * 4 + rr;
        int row0 = win * 49 + tok;
        if (tok < NWIN)
          ao[row0 * 384 + (((gr0 ^ (row0 & 7)) << 3) | (c & 7))] = f2bf(pacc2[dt][rr]);
      }
    }
    __syncthreads();
  }

  __syncthreads();
  for (int nb = 0; nb < 4; ++nb) {
    f32x4 acc[2][3] = {};
    const int pb0 = (nb * 3) & 1;
    compute_proj(0, pb0, acc);
    __syncthreads();
    stage_proj(nb, 2, pb0);
    compute_proj(1, pb0 ^ 1, acc);
    __syncthreads();
    if (nb < 3) stage_proj(nb + 1, 0, pb0 ^ 1);
    compute_proj(2, pb0, acc);
    __syncthreads();
    if (nb < 3) stage_proj(nb + 1, 1, pb0);
    #pragma unroll
    for (int nt = 0; nt < 3; ++nt) {
      int col = nb * 96 + (wn * 3 + nt) * 16 + c;
      float pb = proj_b[col];
      #pragma unroll
      for (int mt = 0; mt < 2; ++mt) {
        #pragma unroll
        for (int r = 0; r < 4; ++r) {
          int mrow = wm * 32 + mt * 16 + g * 4 + r;
          if (mrow < 98) {
            int wi = mrow >= NWIN;
            int tok = mrow - (wi ? NWIN : 0);
            out[((size_t)((blk << 1) + wi) * NWIN + tok) * DIM + col] = acc[mt][nt][r] + pb;
          }
        }
      }
    }
  }
}

extern "C" void kernel_launch(void* const* d_in, const int* in_sizes, int n_in,
                              void* d_out, int out_size, void* d_ws, size_t ws_size,
                              hipStream_t stream) {
  const float* x          = (const float*)d_in[0];
  const float* mask       = (const float*)d_in[1];
  const float* bias_table = (const float*)d_in[2];
  const float* qkv_w      = (const float*)d_in[3];
  const float* qkv_b      = (const float*)d_in[4];
  const float* proj_w     = (const float*)d_in[5];
  const float* proj_b     = (const float*)d_in[6];
  const int*   rel_index  = (const int*)d_in[7];
  float* out = (float*)d_out;

  // ws: wqb @0 | wpb @884736 | qbF @1179648 | bmF @1184256 |
  //     qg @13767168 | kg @167907840 | vg @322048512 | xbf @476189184 | end 630329856
  ushort* wqb = (ushort*)d_ws;
  ushort* wpb = (ushort*)((char*)d_ws + 884736);
  float*  qbF = (float*)((char*)d_ws + 1179648);
  float*  bmF = (float*)((char*)d_ws + 1184256);
  ushort* qg  = (ushort*)((char*)d_ws + 13767168);
  ushort* kg  = (ushort*)((char*)d_ws + 167907840);
  ushort* vg  = (ushort*)((char*)d_ws + 322048512);
  ushort* xbf = (ushort*)((char*)d_ws + 476189184);
  const size_t NEED1 = 630329856ull;          // with xbf (tier-1)
  const size_t NEED2 = 476189184ull;          // r10 layout (tier-2)

  prep_kernel<<<1024, 256, 0, stream>>>(qkv_w, proj_w, bias_table, rel_index, mask, qkv_b,
                                        wqb, wpb, qbF, bmF);

  if (ws_size >= NEED1) {
    x2bf_kernel<<<75264, 256, 0, stream>>>(x, xbf);
    hipFuncSetAttribute((const void*)qkv_gemm_bf16_kernel,
                        hipFuncAttributeMaxDynamicSharedMemorySize, 65536);
    qkv_gemm_bf16_kernel<<<14112, 256, 65536, stream>>>(xbf, qbF, wqb, qg, kg, vg);
    attn_kernel<<<12288, 256, 0, stream>>>(kg, vg, bmF, qg);
    hipFuncSetAttribute((const void*)proj_kernel,
                        hipFuncAttributeMaxDynamicSharedMemorySize, 65536);
    proj_kernel<<<4704, 256, 65536, stream>>>(qg, wpb, proj_b, out);
  } else if (ws_size >= NEED2) {
    hipFuncSetAttribute((const void*)qkv_gemm_kernel,
                        hipFuncAttributeMaxDynamicSharedMemorySize, 65536);
    qkv_gemm_kernel<<<14112, 256, 65536, stream>>>(x, qbF, wqb, qg, kg, vg);
    attn_kernel<<<12288, 256, 0, stream>>>(kg, vg, bmF, qg);
    hipFuncSetAttribute((const void*)proj_kernel,
                        hipFuncAttributeMaxDynamicSharedMemorySize, 65536);
    proj_kernel<<<4704, 256, 65536, stream>>>(qg, wpb, proj_b, out);
  } else {
    hipFuncSetAttribute((const void*)winattn_fused,
                        hipFuncAttributeMaxDynamicSharedMemorySize, FSMEM_US * 2);
    winattn_fused<<<2048, 512, FSMEM_US * 2, stream>>>(x, qbF, proj_b, wqb, wpb, bmF, out);
  }
}